// Round 5
// baseline (1166.690 us; speedup 1.0000x reference)
//
#include <hip/hip_runtime.h>

#define BATCH 512
#define NNODE 200
#define CIN   200
#define HID   128
#define IPY   232   // padded row stride (shorts): 464B rows -> conflict-free ds_read_b128
#define KCH   7     // 7 K-chunks of 32 (cover 224 >= 200)

typedef __attribute__((ext_vector_type(4))) float  f32x4;
typedef __attribute__((ext_vector_type(4))) int    i32x4;
typedef __attribute__((ext_vector_type(8))) short  sh8;
typedef __attribute__((ext_vector_type(4))) short  sh4;
typedef __attribute__((ext_vector_type(8))) __bf16 bf16x8;

__device__ __forceinline__ short f2bf(float x) {
  union { float f; unsigned u; } v; v.f = x;
  unsigned r = v.u + 0x7FFFu + ((v.u >> 16) & 1u);   // RNE
  return (short)(r >> 16);
}
__device__ __forceinline__ float bf2f(short s) {
  union { unsigned u; float f; } v; v.u = ((unsigned)(unsigned short)s) << 16;
  return v.f;
}
__device__ __forceinline__ f32x4 mfma16(sh8 a, sh8 b, f32x4 c) {
  return __builtin_amdgcn_mfma_f32_16x16x32_bf16(
      __builtin_bit_cast(bf16x8, a), __builtin_bit_cast(bf16x8, b), c, 0, 0, 0);
}
__device__ __forceinline__ f32x4 mfma16i(sh8 a, i32x4 b, f32x4 c) {
  return __builtin_amdgcn_mfma_f32_16x16x32_bf16(
      __builtin_bit_cast(bf16x8, a), __builtin_bit_cast(bf16x8, b), c, 0, 0, 0);
}
// expand 8 adjacency bits -> 4 dwords of packed {bf16(b_even)|bf16(b_odd)<<16}
__device__ __forceinline__ i32x4 expand8(unsigned byte_) {
  i32x4 w;
#pragma unroll
  for (int h = 0; h < 4; ++h) {
    unsigned p = byte_ >> (2 * h);
    unsigned d = ((p & 1u) ? 0x3F80u : 0u) | ((p & 2u) ? 0x3F800000u : 0u);
    w[h] = (int)d;
  }
  return w;
}

// ---------- k_prep: W1 [200][128] f32 -> W1T [128][232] bf16 (zero-padded cols) ----------
__global__ __launch_bounds__(256) void k_prep(const float* __restrict__ W1,
                                              short* __restrict__ W1T) {
  const int idx = blockIdx.x * 256 + threadIdx.x;
  const int f = idx / IPY, c = idx - f * IPY;
  W1T[idx] = (c < CIN) ? f2bf(W1[(size_t)c * HID + f]) : (short)0;
}

// ---------- k_gin: grid 256, 2 batches/block; b1 adj ingest pipelined under b0 compute ----
// 13 compute waves + 3 ingest waves; slab double-buffered (1 barrier/ft); W1T staged once.
// NO launch_bounds min-occupancy: r4 showed a 64-VGPR cap spills af/px to scratch (123 MB).
__global__ __launch_bounds__(1024) void k_gin(const float* __restrict__ x,
                                              const int* __restrict__ adj,
                                              const short* __restrict__ W1Tg,
                                              const float* __restrict__ b1g,
                                              const float* __restrict__ W2,
                                              const float* __restrict__ b2g,
                                              const float* __restrict__ eps1p,
                                              const float* __restrict__ eps2p,
                                              float* __restrict__ out) {
  __shared__ __align__(16) short    ls_w1t[HID * IPY];      // 59,392 B
  __shared__ __align__(16) short    ls_slab[2][16 * IPY];   // 14,848 B (double-buffered)
  __shared__ __align__(16) unsigned ls_bits[2][KCH * 224];  // 12,544 B (b0 / b1)
  __shared__ __align__(16) float    ls_deg[2][224];         //  1,792 B
  __shared__ __align__(16) float    ls_w2b1[384];           //  1,536 B  [0,128)=b1, rest W2
  __shared__               float    ls_part[13][2];         //    104 B     total ~90.2 KB

  const int bq   = blockIdx.x;
  const int b0   = bq * 2, b1 = b0 + 1;
  const int tid  = threadIdx.x;
  const int wave = tid >> 6, lane = tid & 63;
  const int lq   = lane >> 4, lm = lane & 15;
  const int j    = wave * 16 + lm;                    // compute-wave column
  const float e1p = 1.f + eps1p[0], e2 = eps2p[0];
  const int* adjb0 = adj + (size_t)b0 * NNODE * NNODE;
  const int* adjb1 = adj + (size_t)b1 * NNODE * NNODE;

  // -------- persistent per-thread state --------
  sh8 af[KCH];                                        // x fragments (28 VGPR)
  f32x4 px0[KCH], px1[KCH];                           // raw x prefetch (live ft6..ft7 only)
  unsigned by[KCH];                                   // adjacency bytes for column j
  float ga = 0.f, gb = 0.f;
  int vA[4][8], vB[4][8];                             // ingest load ping-pong (ingest path)
  unsigned aw0 = 0, aw1 = 0, aw2 = 0, aw3 = 0;        // bit-word accumulators
  const int iwd0 = (wave - 13) * 2;                   // ingest wave's first word index
  const int nbw  = (wave == 15) ? 9 : 8;              // batches per ingest wave
  const int jc3  = min(192 + lane, NNODE - 1);

  // -------- ingest helpers (wave-uniform control; ballots convergent per wave) --------
  auto ing_issue = [&](const int* adjs, int g, int (&v)[4][8]) {
    const int wd = iwd0 + (g >> 2);
    const int r0 = wd * 32 + (g & 3) * 8;
#pragma unroll
    for (int rr = 0; rr < 8; ++rr) {                  // 32 independent loads in flight
      const int* rp = adjs + (size_t)(r0 + rr) * NNODE;
      v[0][rr] = rp[lane]; v[1][rr] = rp[64 + lane];
      v[2][rr] = rp[128 + lane]; v[3][rr] = rp[jc3];
    }
  };
  auto ing_proc = [&](int g, int (&v)[4][8], unsigned* bitsd, float* degd) {
    const int wd = iwd0 + (g >> 2);
    const int t8 = (g & 3) * 8;
    const int tmax = (wd == 6) ? 8 : 32;
#pragma unroll
    for (int rr = 0; rr < 8; ++rr) {                  // pack + ballot-deg
      const int t = t8 + rr;
      const unsigned c0_ = (unsigned)v[0][rr] & 1u;
      const unsigned c1_ = (unsigned)v[1][rr] & 1u;
      const unsigned c2_ = (unsigned)v[2][rr] & 1u;
      const unsigned c3_ = (lane < 8) ? ((unsigned)v[3][rr] & 1u) : 0u;
      aw0 |= c0_ << t; aw1 |= c1_ << t; aw2 |= c2_ << t; aw3 |= c3_ << t;
      const int dg = __popcll(__ballot(c0_ != 0u)) + __popcll(__ballot(c1_ != 0u))
                   + __popcll(__ballot(c2_ != 0u)) + __popcll(__ballot(c3_ != 0u));
      if (lane == 0) degd[wd * 32 + t] = (float)dg;
    }
    if (t8 + 8 >= tmax) {                             // word complete -> store, reset
      unsigned* bp = &bitsd[wd * 224];                // bank = j%32: conflict-free
      bp[lane] = aw0; bp[64 + lane] = aw1; bp[128 + lane] = aw2;
      if (lane < 32) bp[192 + lane] = aw3;            // cols 200-223 stay zero (lane>=8 mask)
      aw0 = aw1 = aw2 = aw3 = 0;
    }
  };

  // -------- compute helpers --------
  auto px_issue = [&](const float* xb) {
    const float* xr = xb + (size_t)min(wave * 16 + lm, NNODE - 1) * CIN;
#pragma unroll
    for (int k = 0; k < KCH; ++k) {
      const int c0 = k * 32 + lq * 8;
      f32x4 z = {0.f, 0.f, 0.f, 0.f};
      px0[k] = z; px1[k] = z;
      if (c0 < CIN) { px0[k] = *(const f32x4*)(xr + c0); px1[k] = *(const f32x4*)(xr + c0 + 4); }
    }
  };
  auto px_conv = [&]() {
#pragma unroll
    for (int k = 0; k < KCH; ++k) {
      sh8 a;
#pragma unroll
      for (int jj = 0; jj < 4; ++jj) { a[jj] = f2bf(px0[k][jj]); a[4 + jj] = f2bf(px1[k][jj]); }
      af[k] = a;
    }
  };
  auto load_by = [&](const unsigned* bs) {
#pragma unroll
    for (int k = 0; k < KCH; ++k) by[k] = (bs[k * 224 + j] >> (lq * 8)) & 0xFFu;
  };
  auto phase1 = [&](int ftt, short* slab) {           // y-slab for f-tile ftt
    const int fb = ftt * 16;
    const short* wr = &ls_w1t[(fb + lm) * IPY];       // conflict-free b128
    f32x4 acc = {0.f, 0.f, 0.f, 0.f};
#pragma unroll
    for (int k = 0; k < KCH; ++k)
      acc = mfma16(af[k], *(const sh8*)(wr + k * 32 + lq * 8), acc);
    sh4 st;                                           // D: n=lm->f_rel, m=lq*4+r
#pragma unroll
    for (int r = 0; r < 4; ++r) st[r] = f2bf(acc[r]);
    *(sh4*)&slab[lm * IPY + wave * 16 + lq * 4] = st; // col <= 207
  };
  auto phase2 = [&](int ftt, const short* slab) {     // agg + eps self + MLP2 partial
    const int fb = ftt * 16;
    const short* yr = &slab[lm * IPY];                // conflict-free b128
    f32x4 accP = {0.f, 0.f, 0.f, 0.f};
#pragma unroll
    for (int k = 0; k < KCH; ++k)
      accP = mfma16i(*(const sh8*)(yr + k * 32 + lq * 8), expand8(by[k]), accP);
#pragma unroll
    for (int r = 0; r < 4; ++r) {
      const int f = fb + lq * 4 + r;
      const float yself = bf2f(slab[(lq * 4 + r) * IPY + j]);  // y[f][j]
      const float h = fmaxf(accP[r] + e1p * yself + ls_w2b1[f], 0.f);
      ga += h * ls_w2b1[128 + 2 * f];
      gb += h * ls_w2b1[129 + 2 * f];
    }
  };
  auto reduceg = [&](const float* degs) {
    ga += __shfl_xor(ga, 16); ga += __shfl_xor(ga, 32);
    gb += __shfl_xor(gb, 16); gb += __shfl_xor(gb, 32);
    const float wj = 1.f + e2 + degs[min(j, NNODE - 1)];
    float t0 = (j < NNODE) ? wj * ga : 0.f;
    float t1 = (j < NNODE) ? wj * gb : 0.f;
#pragma unroll
    for (int d = 1; d < 16; d <<= 1) { t0 += __shfl_xor(t0, d); t1 += __shfl_xor(t1, d); }
    if (lane == 0) { ls_part[wave][0] = t0; ls_part[wave][1] = t1; }
  };

  // ================= phase A: b0 ingest (pipelined) | W1T + x(b0) + W2/b1 stage =========
  if (wave >= 13) {
    ing_issue(adjb0, 0, vA);
#pragma unroll
    for (int g = 0; g < 9; ++g) {
      if (g + 1 < nbw) { if ((g + 1) & 1) ing_issue(adjb0, g + 1, vB); else ing_issue(adjb0, g + 1, vA); }
      if (g < nbw)     { if (g & 1) ing_proc(g, vB, ls_bits[0], ls_deg[0]); else ing_proc(g, vA, ls_bits[0], ls_deg[0]); }
    }
  } else {
    sh8 sc[5];
    int chs[5];
#pragma unroll
    for (int it = 0; it < 5; ++it) {                  // 58 W1T chunks over 13 waves
      chs[it] = wave + it * 13;
      if (chs[it] < 58) sc[it] = ((const sh8*)W1Tg)[chs[it] * 64 + lane];
    }
    px_issue(x + (size_t)b0 * NNODE * CIN);           // issued under staging latency
    float wv = 0.f;
    if (tid < 384) wv = (tid < 128) ? b1g[tid] : W2[tid - 128];
#pragma unroll
    for (int it = 0; it < 5; ++it)
      if (chs[it] < 58) ((sh8*)ls_w1t)[chs[it] * 64 + lane] = sc[it];
    if (tid < 128) {                                  // zero pad cols of BOTH slabs
      const int sb = tid >> 6, q = tid & 63;
      const int rw = q >> 2, p = q & 3;
      sh8 z = {0, 0, 0, 0, 0, 0, 0, 0};
      *(sh8*)&ls_slab[sb][rw * IPY + 200 + p * 8] = z;
    }
    if (tid < 384) ls_w2b1[tid] = wv;
    px_conv();                                        // af = x(b0) bf16
  }
  __syncthreads();

  // ================= prologue b0: first slab | ingest: prime b1 batch 0 =================
  if (wave < 13) { load_by(ls_bits[0]); phase1(0, ls_slab[0]); }
  else           { ing_issue(adjb1, 0, vA); }
  __syncthreads();

  // ================= b0 ft loop (8 barriers) with pipelined b1 ingest =================
#pragma unroll
  for (int ft = 0; ft < 8; ++ft) {
    if (wave < 13) {
      if (ft < 7) phase1(ft + 1, ls_slab[(ft + 1) & 1]);
      if (ft == 6) px_issue(x + (size_t)b1 * NNODE * CIN);   // b1 x prefetch (af dead after this phase1)
      phase2(ft, ls_slab[ft & 1]);
      if (ft == 7) px_conv();                                // af = x(b1) bf16
    } else {
      if ((ft & 1) == 0) { if (ft + 1 < nbw) ing_issue(adjb1, ft + 1, vB); ing_proc(ft, vA, ls_bits[1], ls_deg[1]); }
      else               { if (ft + 1 < nbw) ing_issue(adjb1, ft + 1, vA); ing_proc(ft, vB, ls_bits[1], ls_deg[1]); }
    }
    __syncthreads();
  }

  // ================= epilogue b0 | ingest wave 15: final b1 batch =================
  if (wave < 13)      reduceg(ls_deg[0]);
  else if (wave == 15) ing_proc(8, vA, ls_bits[1], ls_deg[1]);
  __syncthreads();

  // ================= prologue b1 + out[b0] =================
  if (wave < 13) { load_by(ls_bits[1]); ga = 0.f; gb = 0.f; phase1(0, ls_slab[0]); }
  if (tid < 2) {
    float s = 0.f;
#pragma unroll
    for (int q = 0; q < 13; ++q) s += ls_part[q][tid];
    out[b0 * 2 + tid] = b2g[tid] + s * (1.f / NNODE); // fully overwritten, no atomics
  }
  __syncthreads();

  // ================= b1 ft loop (8 barriers) =================
#pragma unroll
  for (int ft = 0; ft < 8; ++ft) {
    if (wave < 13) {
      if (ft < 7) phase1(ft + 1, ls_slab[(ft + 1) & 1]);
      phase2(ft, ls_slab[ft & 1]);
    }
    __syncthreads();
  }

  if (wave < 13) reduceg(ls_deg[1]);
  __syncthreads();
  if (tid < 2) {
    float s = 0.f;
#pragma unroll
    for (int q = 0; q < 13; ++q) s += ls_part[q][tid];
    out[b1 * 2 + tid] = b2g[tid] + s * (1.f / NNODE);
  }
}

extern "C" void kernel_launch(void* const* d_in, const int* in_sizes, int n_in,
                              void* d_out, int out_size, void* d_ws, size_t ws_size,
                              hipStream_t stream) {
  const float* x    = (const float*)d_in[0];
  const int*   adj  = (const int*)d_in[1];
  const float* W1   = (const float*)d_in[2];
  const float* b1   = (const float*)d_in[3];
  const float* W2   = (const float*)d_in[4];
  const float* b2   = (const float*)d_in[5];
  const float* eps1 = (const float*)d_in[6];
  const float* eps2 = (const float*)d_in[7];
  float* out = (float*)d_out;

  short* W1T = (short*)d_ws;                          // 59,392 B

  k_prep<<<116, 256, 0, stream>>>(W1, W1T);
  k_gin <<<BATCH / 2, 1024, 0, stream>>>(x, adj, W1T, b1, W2, b2, eps1, eps2, out);
}

// Round 6
// 214.772 us; speedup vs baseline: 5.4322x; 5.4322x over previous
//
#include <hip/hip_runtime.h>

#define BATCH 512
#define NNODE 200
#define CIN   200
#define HID   128
#define IPY   232   // padded row stride (shorts): 464B rows -> conflict-free ds_read_b128
#define KCH   7     // 7 K-chunks of 32 (cover 224 >= 200)

typedef __attribute__((ext_vector_type(4))) float  f32x4;
typedef __attribute__((ext_vector_type(4))) int    i32x4;
typedef __attribute__((ext_vector_type(8))) short  sh8;
typedef __attribute__((ext_vector_type(4))) short  sh4;
typedef __attribute__((ext_vector_type(8))) __bf16 bf16x8;

__device__ __forceinline__ short f2bf(float x) {
  union { float f; unsigned u; } v; v.f = x;
  unsigned r = v.u + 0x7FFFu + ((v.u >> 16) & 1u);   // RNE
  return (short)(r >> 16);
}
__device__ __forceinline__ float bf2f(short s) {
  union { unsigned u; float f; } v; v.u = ((unsigned)(unsigned short)s) << 16;
  return v.f;
}
__device__ __forceinline__ f32x4 mfma16(sh8 a, sh8 b, f32x4 c) {
  return __builtin_amdgcn_mfma_f32_16x16x32_bf16(
      __builtin_bit_cast(bf16x8, a), __builtin_bit_cast(bf16x8, b), c, 0, 0, 0);
}
__device__ __forceinline__ f32x4 mfma16i(sh8 a, i32x4 b, f32x4 c) {
  return __builtin_amdgcn_mfma_f32_16x16x32_bf16(
      __builtin_bit_cast(bf16x8, a), __builtin_bit_cast(bf16x8, b), c, 0, 0, 0);
}
// expand 8 adjacency bits -> 4 dwords of packed {bf16(b_even)|bf16(b_odd)<<16}
__device__ __forceinline__ i32x4 expand8(unsigned byte_) {
  i32x4 w;
#pragma unroll
  for (int h = 0; h < 4; ++h) {
    unsigned p = byte_ >> (2 * h);
    unsigned d = ((p & 1u) ? 0x3F80u : 0u) | ((p & 2u) ? 0x3F800000u : 0u);
    w[h] = (int)d;
  }
  return w;
}

// ---------- k_prep: W1 [200][128] f32 -> W1T [128][232] bf16 (zero-padded cols) ----------
__global__ __launch_bounds__(256) void k_prep(const float* __restrict__ W1,
                                              short* __restrict__ W1T) {
  const int idx = blockIdx.x * 256 + threadIdx.x;
  const int f = idx / IPY, c = idx - f * IPY;
  W1T[idx] = (c < CIN) ? f2bf(W1[(size_t)c * HID + f]) : (short)0;
}

// ---------- k_gin: one block per batch; slab-fused phases; LDS 75.6 KB ----------
// == r4 kernel with the (1024,8) occupancy cap REMOVED: r4 proved the cap (64-unified,
// split arch=32) spills phase A (123 MB scratch); r3 proved the identical phase A fits
// ~52 regs uncapped. LDS already fits 2 blocks/CU (2x75.6 <= 160 KB); if natural VGPR
// allocation lands <=64, hardware grants 2 blocks/CU without coercion.
__global__ __launch_bounds__(1024) void k_gin(const float* __restrict__ x,
                                              const int* __restrict__ adj,
                                              const short* __restrict__ W1Tg,
                                              const float* __restrict__ b1,
                                              const float* __restrict__ W2,
                                              const float* __restrict__ b2,
                                              const float* __restrict__ eps1p,
                                              const float* __restrict__ eps2p,
                                              float* __restrict__ out) {
  __shared__ __align__(16) short    ls_w1t[HID * IPY];   // 59,392 B
  __shared__ __align__(16) short    ls_slab[16 * IPY];   //  7,424 B  y-slab for current ft
  __shared__ __align__(16) unsigned ls_bits[KCH * 224];  //  6,272 B  [wd][j]
  __shared__ __align__(16) float    ls_deg[224];         //    896 B
  __shared__ __align__(16) float    ls_w2b1[384];        //  1,536 B  [0,128)=b1, [128,384)=W2
  __shared__               float    ls_part[13][2];      //    104 B

  const int b    = blockIdx.x;
  const int tid  = threadIdx.x;
  const int wave = tid >> 6, lane = tid & 63;
  const int lq   = lane >> 4, lm = lane & 15;
  const int* adjb = adj + (size_t)b * NNODE * NNODE;

  sh8 af[KCH];                                           // x fragments (28 VGPR, persistent)

  if (wave >= 13) {
    // ============ adj ingest, 3 waves: rows 0-63 / 64-127 / 128-199 ============
    const int iw  = wave - 13;
    const int wd0 = iw * 2, wd1 = (iw == 2) ? 7 : iw * 2 + 2;
    const int jc3 = min(192 + lane, NNODE - 1);
    for (int wd = wd0; wd < wd1; ++wd) {
      const int tmax = (wd == 6) ? 8 : 32;
      unsigned w0 = 0, w1 = 0, w2 = 0, w3 = 0;
      for (int t8 = 0; t8 < tmax; t8 += 8) {
        int v0[8], v1[8], v2[8], v3[8];
#pragma unroll
        for (int rr = 0; rr < 8; ++rr) {                 // 32 independent loads in flight
          const int* rp = adjb + (wd * 32 + t8 + rr) * NNODE;
          v0[rr] = rp[lane]; v1[rr] = rp[64 + lane];
          v2[rr] = rp[128 + lane]; v3[rr] = rp[jc3];
        }
#pragma unroll
        for (int rr = 0; rr < 8; ++rr) {                 // pack + ballot-deg
          const int t = t8 + rr;
          const unsigned b0 = (unsigned)v0[rr] & 1u;
          const unsigned b1_ = (unsigned)v1[rr] & 1u;
          const unsigned b2_ = (unsigned)v2[rr] & 1u;
          const unsigned b3_ = (lane < 8) ? ((unsigned)v3[rr] & 1u) : 0u;
          w0 |= b0 << t; w1 |= b1_ << t; w2 |= b2_ << t; w3 |= b3_ << t;
          const int dg = __popcll(__ballot(b0 != 0u)) + __popcll(__ballot(b1_ != 0u))
                       + __popcll(__ballot(b2_ != 0u)) + __popcll(__ballot(b3_ != 0u));
          if (lane == 0) ls_deg[wd * 32 + t] = (float)dg;
        }
      }
      unsigned* bp = &ls_bits[wd * 224];                 // bank = j%32: conflict-free
      bp[lane] = w0; bp[64 + lane] = w1; bp[128 + lane] = w2;
      if (lane < 32) bp[192 + lane] = w3;                // zeroes pad cols 200-223 too
    }
  } else {
    // ============ stage W1T + x gather + W2/b1 stage + slab-pad zero + bf16 conv ============
    sh8 sc[5];
    int chs[5];
#pragma unroll
    for (int it = 0; it < 5; ++it) {                     // 58 chunks over 13 waves
      chs[it] = wave + it * 13;
      if (chs[it] < 58) sc[it] = ((const sh8*)W1Tg)[chs[it] * 64 + lane];
    }
    f32x4 px0[KCH], px1[KCH];                            // issued before stage writes
    const int row = min(wave * 16 + lm, NNODE - 1);
    const float* xr = x + (size_t)b * NNODE * CIN + (size_t)row * CIN;
#pragma unroll
    for (int k = 0; k < KCH; ++k) {
      const int c0 = k * 32 + lq * 8;
      f32x4 z = {0.f, 0.f, 0.f, 0.f};
      px0[k] = z; px1[k] = z;
      if (c0 < CIN) { px0[k] = *(const f32x4*)(xr + c0); px1[k] = *(const f32x4*)(xr + c0 + 4); }
    }
    float wv = 0.f;
    if (tid < 384) wv = (tid < 128) ? b1[tid] : W2[tid - 128];
#pragma unroll
    for (int it = 0; it < 5; ++it)                       // waits only on sc loads
      if (chs[it] < 58) ((sh8*)ls_w1t)[chs[it] * 64 + lane] = sc[it];
    if (tid < 64) {                                      // zero slab cols 200-231 (never else)
      const int rw = tid >> 2, p = tid & 3;
      sh8 z = {0, 0, 0, 0, 0, 0, 0, 0};
      *(sh8*)&ls_slab[rw * IPY + 200 + p * 8] = z;
    }
    if (tid < 384) ls_w2b1[tid] = wv;
#pragma unroll
    for (int k = 0; k < KCH; ++k) {                      // px dies here; af = 28 VGPRs
      sh8 a;
#pragma unroll
      for (int jj = 0; jj < 4; ++jj) { a[jj] = f2bf(px0[k][jj]); a[4 + jj] = f2bf(px1[k][jj]); }
      af[k] = a;
    }
  }
  __syncthreads();

  // ================= fused ft loop: phase1(slab) | barrier | phase2(agg+MLP2) =================
  const float e1 = eps1p[0], e2 = eps2p[0];
  const int j = wave * 16 + lm;                          // this wave's jt == mt == wave
  unsigned by[KCH];                                      // adjacency bytes (7 VGPR)
  if (wave < 13) {
#pragma unroll
    for (int k = 0; k < KCH; ++k) by[k] = (ls_bits[k * 224 + j] >> (lq * 8)) & 0xFFu;
  }
  float ga = 0.f, gb = 0.f;

  for (int ft = 0; ft < 8; ++ft) {
    const int fb = ft * 16;
    if (wave < 13) {
      // ---- phase 1: y-slab[f-rel][m] for this ft ----
      const short* wr = &ls_w1t[(fb + lm) * IPY];        // conflict-free b128
      f32x4 acc = {0.f, 0.f, 0.f, 0.f};
#pragma unroll
      for (int k = 0; k < KCH; ++k)
        acc = mfma16(af[k], *(const sh8*)(wr + k * 32 + lq * 8), acc);
      sh4 st;                                            // D: n=lm->f_rel, m=lq*4+r
#pragma unroll
      for (int r = 0; r < 4; ++r) st[r] = f2bf(acc[r]);
      *(sh4*)&ls_slab[lm * IPY + wave * 16 + lq * 4] = st;   // col <= 207; cols>=200 hit
    }                                                        // zero adjacency bits anyway
    __syncthreads();
    if (wave < 13) {
      // ---- phase 2: agg over m + eps self-term + MLP2 partial ----
      const short* yr = &ls_slab[lm * IPY];              // A rows = f_rel = lm
      f32x4 accP = {0.f, 0.f, 0.f, 0.f};
#pragma unroll
      for (int k = 0; k < KCH; ++k)
        accP = mfma16i(*(const sh8*)(yr + k * 32 + lq * 8), expand8(by[k]), accP);
#pragma unroll
      for (int r = 0; r < 4; ++r) {
        const int f = fb + lq * 4 + r;
        const float yself = bf2f(ls_slab[(lq * 4 + r) * IPY + j]);   // y[f][j]
        const float h = fmaxf(accP[r] + (1.f + e1) * yself + ls_w2b1[f], 0.f);
        ga += h * ls_w2b1[128 + 2 * f];
        gb += h * ls_w2b1[129 + 2 * f];
      }
    }
    __syncthreads();
  }

  if (wave < 13) {
    ga += __shfl_xor(ga, 16); ga += __shfl_xor(ga, 32);  // sum over lq -> full f-sum per j
    gb += __shfl_xor(gb, 16); gb += __shfl_xor(gb, 32);
    const bool jok = (j < NNODE);
    const float wj = 1.f + e2 + ls_deg[min(j, NNODE - 1)];
    float t0 = jok ? wj * ga : 0.f;
    float t1 = jok ? wj * gb : 0.f;
#pragma unroll
    for (int d = 1; d < 16; d <<= 1) { t0 += __shfl_xor(t0, d); t1 += __shfl_xor(t1, d); }
    if (lane == 0) { ls_part[wave][0] = t0; ls_part[wave][1] = t1; }
  }
  __syncthreads();

  if (tid < 2) {                                         // out fully overwritten, no atomics
    float s = 0.f;
#pragma unroll
    for (int q = 0; q < 13; ++q) s += ls_part[q][tid];
    out[b * 2 + tid] = b2[tid] + s * (1.f / NNODE);
  }
}

extern "C" void kernel_launch(void* const* d_in, const int* in_sizes, int n_in,
                              void* d_out, int out_size, void* d_ws, size_t ws_size,
                              hipStream_t stream) {
  const float* x    = (const float*)d_in[0];
  const int*   adj  = (const int*)d_in[1];
  const float* W1   = (const float*)d_in[2];
  const float* b1   = (const float*)d_in[3];
  const float* W2   = (const float*)d_in[4];
  const float* b2   = (const float*)d_in[5];
  const float* eps1 = (const float*)d_in[6];
  const float* eps2 = (const float*)d_in[7];
  float* out = (float*)d_out;

  short* W1T = (short*)d_ws;                             // 59,392 B

  k_prep<<<116, 256, 0, stream>>>(W1, W1T);
  k_gin <<<BATCH, 1024, 0, stream>>>(x, adj, W1T, b1, W2, b2, eps1, eps2, out);
}